// Round 3
// baseline (592.007 us; speedup 1.0000x reference)
//
#include <hip/hip_runtime.h>
#include <hip/hip_bf16.h>
#include <stdint.h>

#define BB 4
#define SS 2048
#define DD 2048
#define HH 16
#define HD 128
#define MTOT (BB*SS)   // 8192 rows for both big GEMMs

typedef __attribute__((ext_vector_type(8))) short short8;   // 8 bf16 (4 VGPRs)
typedef __attribute__((ext_vector_type(4))) float f32x4;    // MFMA C/D

__device__ __forceinline__ unsigned short f2bf(float f) {
    union { float f; unsigned int u; } v; v.f = f;
    unsigned int u = v.u;
    return (unsigned short)((u + 0x7FFFu + ((u >> 16) & 1u)) >> 16);  // RNE
}
// cheap round-half-up for nonnegative P values (2 VALU instead of 4)
__device__ __forceinline__ unsigned short f2bf_ru(float f) {
    union { float f; unsigned int u; } v; v.f = f;
    return (unsigned short)((v.u + 0x8000u) >> 16);
}

// ---------------------------------------------------------------- converts
__global__ __launch_bounds__(256) void convert_kernel(
    const float* __restrict__ src, unsigned short* __restrict__ dst, int n4) {
    int i = blockIdx.x * 256 + threadIdx.x;
    if (i >= n4) return;
    float4 v = ((const float4*)src)[i];
    unsigned int lo = (unsigned int)f2bf(v.x) | ((unsigned int)f2bf(v.y) << 16);
    unsigned int hi = (unsigned int)f2bf(v.z) | ((unsigned int)f2bf(v.w) << 16);
    ((uint2*)dst)[i] = make_uint2(lo, hi);
}

// RoPE on query + bf16 convert. One thread per (even,odd) pair.
__global__ __launch_bounds__(256) void rope_q_kernel(
    const float* __restrict__ q, const float* __restrict__ fc,
    const float* __restrict__ fs, unsigned short* __restrict__ dst) {
    int idx = blockIdx.x * 256 + threadIdx.x;          // pair index, 0..B*S*D/2
    int row   = idx >> 10;                             // b*S + s
    int s     = row & (SS - 1);
    int p     = idx & 63;                              // pos within head /2
    float2 t = ((const float2*)q)[idx];
    float c = fc[s*64 + p], sn = fs[s*64 + p];
    float o1 = t.x*c - t.y*sn;
    float o2 = t.x*sn + t.y*c;
    ((unsigned int*)dst)[idx] = (unsigned int)f2bf(o1) | ((unsigned int)f2bf(o2) << 16);
}

// value (B,S,H,HD) fp32 -> Vt (B,H,HD,S') bf16, where within each 64-s block
// the s-axis is PERMUTED: position k' = 4m+c holds original s = c*16+m.
// This makes attention's P-store a contiguous b64 write (P and V share the
// same k-permutation, so the PV dot product is unchanged).
__global__ __launch_bounds__(256) void transpose_v_kernel(
    const float* __restrict__ v, unsigned short* __restrict__ vt) {
    __shared__ unsigned short tile[64][72];
    int bh = blockIdx.z;                   // b*16 + h
    int s0 = blockIdx.x * 64, d0 = blockIdx.y * 64;
    int t = threadIdx.x;
    #pragma unroll
    for (int it = 0; it < 4; ++it) {
        int i  = it*16 + (t >> 4);         // local s
        int j4 = t & 15;                   // float4 index along d
        float4 f = *(const float4*)(v +
            (((size_t)((bh >> 4)*SS + s0 + i)*HH + (bh & 15))*HD + d0 + j4*4));
        unsigned int lo = (unsigned int)f2bf(f.x) | ((unsigned int)f2bf(f.y) << 16);
        unsigned int hi = (unsigned int)f2bf(f.z) | ((unsigned int)f2bf(f.w) << 16);
        *(uint2*)&tile[i][j4*4] = make_uint2(lo, hi);
    }
    __syncthreads();
    unsigned int* vt32 = (unsigned int*)vt;
    #pragma unroll
    for (int it = 0; it < 8; ++it) {
        int task = it*256 + t;
        int tt = task & 31;                // output dword index within 64-block
        int d  = task >> 5;                // local d, 0..63
        // dword tt covers k' = 2tt, 2tt+1 -> original s = 32(tt&1)+(tt>>1) (+16)
        int slo = ((tt & 1) << 5) + (tt >> 1);
        unsigned int lo = tile[slo][d], hi = tile[slo + 16][d];
        vt32[((size_t)bh*HD + d0 + d)*(SS/2) + (s0 >> 1) + tt] = lo | (hi << 16);
    }
}

// ---------------------------------------------------------------- GEMM
// C[m,n] = sum_k A[m,k]*W[n,k] + bias[n].  A: MxK bf16 row-major, W: NxK bf16.
// MODE 0: fused RoPE epilogue, bf16 out (K projection).
// MODE 1: plain epilogue, fp32 out (output projection).
// XCD-chunked block swizzle (bijective, nwg=1024 % 8 == 0).
template<int MODE>
__global__ __launch_bounds__(256, 2) void gemm_kernel(
    const unsigned short* __restrict__ A, const unsigned short* __restrict__ W,
    const float* __restrict__ bias, const float* __restrict__ fc,
    const float* __restrict__ fs, void* __restrict__ out)
{
    __shared__ unsigned short As[128*32];
    __shared__ unsigned short Bs[128*32];
    const int K = DD;
    int L   = blockIdx.y * 16 + blockIdx.x;          // 0..1023, x-fastest
    int swz = (L & 7) * 128 + (L >> 3);              // XCD -> contiguous chunk
    int m0 = (swz >> 4) * 128, n0 = (swz & 15) * 128;
    int t = threadIdx.x, lane = t & 63, w = t >> 6;
    int wm = w >> 1, wn = w & 1;
    int l15 = lane & 15, quad = lane >> 4;

    f32x4 acc[4][4] = {};

    for (int k0 = 0; k0 < K; k0 += 32) {
        __syncthreads();                    // prior tile's LDS reads done
        #pragma unroll
        for (int i = 0; i < 2; ++i) {
            int ci  = i*256 + t;            // 16B chunk id, 0..511
            int row = ci >> 2;
            int ce  = (ci & 3) * 8;         // elem offset within 32-col row
            const unsigned short* ga = A + (size_t)(m0 + row) * K + k0 + ce;
            const unsigned short* gb = W + (size_t)(n0 + row) * K + k0 + ce;
            unsigned short* la = As + (size_t)(i*256 + w*64) * 8;  // wave-uniform
            unsigned short* lb = Bs + (size_t)(i*256 + w*64) * 8;
            __builtin_amdgcn_global_load_lds(
                (__attribute__((address_space(1))) void*)(uintptr_t)ga,
                (__attribute__((address_space(3))) void*)la, 16, 0, 0);
            __builtin_amdgcn_global_load_lds(
                (__attribute__((address_space(1))) void*)(uintptr_t)gb,
                (__attribute__((address_space(3))) void*)lb, 16, 0, 0);
        }
        __syncthreads();                    // drains vmcnt (global_load_lds)

        short8 af[4], bw[4];
        #pragma unroll
        for (int i = 0; i < 4; ++i) {
            af[i] = *(const short8*)(As + (size_t)(wm*64 + i*16 + l15)*32 + quad*8);
            bw[i] = *(const short8*)(Bs + (size_t)(wn*64 + i*16 + l15)*32 + quad*8);
        }
        #pragma unroll
        for (int i = 0; i < 4; ++i)
            #pragma unroll
            for (int j = 0; j < 4; ++j)
                acc[i][j] = __builtin_amdgcn_mfma_f32_16x16x32_bf16(
                    af[i], bw[j], acc[i][j], 0, 0, 0);
    }

    // epilogue: C/D layout col=lane&15, row=quad*4+reg  [m89-verified]
    #pragma unroll
    for (int i = 0; i < 4; ++i) {
        #pragma unroll
        for (int j = 0; j < 4; ++j) {
            int col = n0 + wn*64 + j*16 + l15;
            float bv = bias[col];
            #pragma unroll
            for (int r = 0; r < 4; ++r) {
                int row = m0 + wm*64 + i*16 + quad*4 + r;
                float v = acc[i][j][r] + bv;
                if (MODE == 0) {
                    // fused RoPE: pair partner is the adjacent lane
                    int s = row & (SS - 1);
                    int p = (col & 127) >> 1;
                    float other = __shfl_xor(v, 1);
                    float c = fc[s*64 + p], sn = fs[s*64 + p];
                    float res = (col & 1) ? (other*sn + v*c) : (v*c - other*sn);
                    ((unsigned short*)out)[(size_t)row*DD + col] = f2bf(res);
                } else {
                    ((float*)out)[(size_t)row*DD + col] = v;
                }
            }
        }
    }
}

// ---------------------------------------------------------------- attention
// Flash-style causal attention. Block = 8 waves / 512 threads; wave w owns
// 16 q-rows of a 128-row q-tile.
// K/V tiles DOUBLE-BUFFERED in LDS: stage(jt+1) is issued right after the
// per-iteration barrier and stays in flight across the whole compute of
// tile jt; the __syncthreads drain then costs ~nothing (loads are L2-hits
// with a full compute phase to land). ONE barrier per iteration.
// LDS rows UNPADDED (wave-uniform glds dest); bank conflicts avoided by an
// XOR chunk swizzle applied on the GLOBAL side (read with exact inverse).
// V's k-axis is pre-permuted in Vt (see transpose_v_kernel) so P-stores are
// contiguous ds_write_b64 (4/iter instead of 16 scalar b16) — conflict-free.
// Defer-max (T13, THR=8 base-2); masked waves skip compute after barrier.
// XCD swizzle: each XCD owns 8 consecutive bh.
__global__ __launch_bounds__(512, 4) void attn_kernel(
    const unsigned short* __restrict__ Q, const unsigned short* __restrict__ Kr,
    const unsigned short* __restrict__ Vt, unsigned short* __restrict__ O)
{
    constexpr int PSTR = 72;
    __shared__ unsigned short Ks[2*64*128];  // K tiles (dbuf), swizzled chunks
    __shared__ unsigned short VTs[2*128*64]; // Vt tiles (dbuf), swizzled chunks
    __shared__ unsigned short Ps[128*PSTR];  // rows [16w,16w+16) private to wave w

    int L   = blockIdx.y * 8 + blockIdx.x;   // 0..511, x-fastest
    int swz = (L & 7) * 64 + (L >> 3);       // XCD -> contiguous 64-block chunk
    int bh   = swz >> 3;                     // XCD x gets bh in [8x, 8x+8)
    int pair = swz & 7;                      // all 8 pairs of each bh

    int b = bh >> 4, h = bh & 15;
    size_t base  = (size_t)b*SS*DD + (size_t)h*HD;   // Q/K/O: + s*DD + d
    size_t vbase = (size_t)bh*HD*SS;                 // Vt: + d*SS + s'

    int t = threadIdx.x, lane = t & 63, w = t >> 6;
    int l15 = lane & 15, quad = lane >> 4;
    int l7 = l15 & 7;

    // scores scaled by 1/sqrt(128)*log2(e) so softmax uses exp2 directly
    const float scl2 = 0.08838834764831845f * 1.44269504088896f;

    // stage K (64x128) + V (128x64) tile jt into buffer buf (4 glds/thread)
    auto stage = [&](int jt, int buf) {
        int j0s = jt * 64;
        #pragma unroll
        for (int i = 0; i < 2; ++i) {
            int ci  = i*512 + t;
            int row = ci >> 4;                 // 0..63
            int cc  = ci & 15;
            int gch = cc ^ (row & 7);          // global chunk (swizzle)
            const unsigned short* ga = Kr + base + (size_t)(j0s + row)*DD + gch*8;
            unsigned short* la = Ks + buf*(64*128) + (size_t)(i*512 + w*64)*8;
            __builtin_amdgcn_global_load_lds(
                (__attribute__((address_space(1))) void*)(uintptr_t)ga,
                (__attribute__((address_space(3))) void*)la, 16, 0, 0);
        }
        #pragma unroll
        for (int i = 0; i < 2; ++i) {
            int ci  = i*512 + t;
            int d   = ci >> 3;                 // 0..127
            int cc  = ci & 7;
            int gch = cc ^ (d & 7);
            const unsigned short* ga = Vt + vbase + (size_t)d*SS + j0s + gch*8;
            unsigned short* la = VTs + buf*(128*64) + (size_t)(i*512 + w*64)*8;
            __builtin_amdgcn_global_load_lds(
                (__attribute__((address_space(1))) void*)(uintptr_t)ga,
                (__attribute__((address_space(3))) void*)la, 16, 0, 0);
        }
    };

    for (int ph = 0; ph < 2; ++ph) {
        int qt = ph ? (15 - pair) : pair;    // iters: (2p+2)+(2(15-p)+2)=34
        int q0 = qt * 128;
        int rw = q0 + w*16;                  // wave's first q-row

        // A-fragment of Q direct from global: m=l15 row, k=quad*8+j offset.
        short8 aq[4];
        #pragma unroll
        for (int kk = 0; kk < 4; ++kk)
            aq[kk] = *(const short8*)(Q + base +
                (size_t)(rw + l15)*DD + kk*32 + quad*8);

        float m_i[4], l_i[4];
        #pragma unroll
        for (int r = 0; r < 4; ++r) { m_i[r] = -1e30f; l_i[r] = 0.f; }
        f32x4 o_acc[8] = {};

        __syncthreads();                     // buffers free (prev phase done)
        stage(0, 0);
        int jmax = 2*qt + 1;

        for (int jt = 0; jt <= jmax; ++jt) {
            int pb = jt & 1;
            int j0 = jt * 64;
            const unsigned short* Kb = Ks  + pb*(64*128);
            const unsigned short* Vb = VTs + pb*(128*64);

            __syncthreads();   // drains own glds(jt) -> buf[pb] ready; buf[pb^1] free
            if (jt < jmax) stage(jt + 1, pb ^ 1);   // overlaps with compute below

            // wave fully above the diagonal for this k-tile -> no compute
            if (j0 > rw + 15) continue;

            // QK^T: wave's 16 q-rows x 64 k-cols
            f32x4 sacc[4];
            #pragma unroll
            for (int c = 0; c < 4; ++c) {
                sacc[c] = (f32x4){0.f, 0.f, 0.f, 0.f};
                #pragma unroll
                for (int kk = 0; kk < 4; ++kk) {
                    short8 bk = *(const short8*)(Kb +
                        (size_t)(c*16 + l15)*128 + ((kk*4 + quad) ^ l7)*8);
                    sacc[c] = __builtin_amdgcn_mfma_f32_16x16x32_bf16(aq[kk], bk, sacc[c], 0,0,0);
                }
            }

            // scale(log2e folded) + causal mask (wave-uniform diag flag)
            bool diag = (j0 + 63 > rw);
            float pp[4][4], mt4[4];
            #pragma unroll
            for (int r = 0; r < 4; ++r) mt4[r] = -1e30f;
            #pragma unroll
            for (int c = 0; c < 4; ++c)
                #pragma unroll
                for (int r = 0; r < 4; ++r) {
                    float v = sacc[c][r] * scl2;
                    if (diag) {
                        int cg = j0 + c*16 + l15;         // global k col
                        int rg = rw + quad*4 + r;         // global q row
                        if (cg > rg) v = -1e30f;
                    }
                    pp[c][r] = v;
                    mt4[r] = fmaxf(mt4[r], v);
                }

            // row-max across the 16 quad lanes + defer-max check
            bool grow = false;
            #pragma unroll
            for (int r = 0; r < 4; ++r) {
                float m = mt4[r];
                m = fmaxf(m, __shfl_xor(m, 1));
                m = fmaxf(m, __shfl_xor(m, 2));
                m = fmaxf(m, __shfl_xor(m, 4));
                m = fmaxf(m, __shfl_xor(m, 8));
                mt4[r] = m;
                grow = grow || (m > m_i[r] + 8.0f);
            }
            if (__any(grow)) {             // rare after the first tiles
                #pragma unroll
                for (int r = 0; r < 4; ++r) {
                    float mn = fmaxf(m_i[r], mt4[r]);
                    float a  = exp2f(m_i[r] - mn);   // alpha
                    m_i[r] = mn;
                    l_i[r] *= a;
                    mt4[r] = a;
                }
                #pragma unroll
                for (int f = 0; f < 8; ++f)
                    #pragma unroll
                    for (int r = 0; r < 4; ++r)
                        o_acc[f][r] *= mt4[r];
            }

            // P = exp2(s - m); packed b64 store: k' = 4*l15 + c (V-matched perm)
            // Wave-private rows, same-wave DS ordering — no barrier needed.
            float rs[4];
            #pragma unroll
            for (int r = 0; r < 4; ++r) {
                float e0 = exp2f(pp[0][r] - m_i[r]);
                float e1 = exp2f(pp[1][r] - m_i[r]);
                float e2 = exp2f(pp[2][r] - m_i[r]);
                float e3 = exp2f(pp[3][r] - m_i[r]);
                rs[r] = (e0 + e1) + (e2 + e3);
                unsigned int lo = (unsigned int)f2bf_ru(e0) | ((unsigned int)f2bf_ru(e1) << 16);
                unsigned int hi = (unsigned int)f2bf_ru(e2) | ((unsigned int)f2bf_ru(e3) << 16);
                *(uint2*)&Ps[(size_t)(w*16 + quad*4 + r)*PSTR + l15*4] = make_uint2(lo, hi);
            }
            #pragma unroll
            for (int r = 0; r < 4; ++r) {
                float s = rs[r];
                s += __shfl_xor(s, 1);
                s += __shfl_xor(s, 2);
                s += __shfl_xor(s, 4);
                s += __shfl_xor(s, 8);
                l_i[r] += s;               // alpha already folded into l_i
            }

            // PV: o += P(16x64) @ V(64x128) in permuted-k space
            #pragma unroll
            for (int kk2 = 0; kk2 < 2; ++kk2) {
                short8 ap = *(const short8*)(Ps + (size_t)(w*16 + l15)*PSTR + kk2*32 + quad*8);
                #pragma unroll
                for (int f = 0; f < 8; ++f) {
                    short8 bv = *(const short8*)(Vb +
                        (size_t)(f*16 + l15)*64 + ((kk2*4 + quad) ^ l7)*8);
                    o_acc[f] = __builtin_amdgcn_mfma_f32_16x16x32_bf16(ap, bv, o_acc[f], 0,0,0);
                }
            }
        }

        // epilogue: normalize and store bf16 (B,S,H,HD)
        #pragma unroll
        for (int f = 0; f < 8; ++f) {
            #pragma unroll
            for (int r = 0; r < 4; ++r) {
                int srow = rw + quad*4 + r;
                int d = f*16 + l15;
                O[base + (size_t)srow*DD + d] = f2bf(o_acc[f][r] / l_i[r]);
            }
        }
    }
}

// ---------------------------------------------------------------- launch
extern "C" void kernel_launch(void* const* d_in, const int* in_sizes, int n_in,
                              void* d_out, int out_size, void* d_ws, size_t ws_size,
                              hipStream_t stream) {
    const float* x      = (const float*)d_in[0];
    const float* query  = (const float*)d_in[1];
    const float* value  = (const float*)d_in[2];
    const float* fc     = (const float*)d_in[3];
    const float* fs     = (const float*)d_in[4];
    const float* key_w  = (const float*)d_in[5];
    const float* key_b  = (const float*)d_in[6];
    const float* proj_w = (const float*)d_in[7];
    const float* proj_b = (const float*)d_in[8];

    const int ND  = BB*SS*DD;      // 16777216
    const int NW  = DD*DD;         // 4194304
    unsigned short* xb  = (unsigned short*)d_ws;   // x bf16
    unsigned short* kwb = xb  + ND;                // key_w bf16
    unsigned short* pwb = kwb + NW;                // proj_w bf16
    unsigned short* qr  = pwb + NW;                // query roped bf16
    unsigned short* vt  = qr  + ND;                // value transposed+permuted bf16
    unsigned short* kr  = vt  + ND;                // k projected+roped bf16
    unsigned short* ao  = xb;                      // attn out reuses x region

    convert_kernel<<<ND/4/256, 256, 0, stream>>>(x, xb, ND/4);
    convert_kernel<<<NW/4/256, 256, 0, stream>>>(key_w, kwb, NW/4);
    convert_kernel<<<NW/4/256, 256, 0, stream>>>(proj_w, pwb, NW/4);
    rope_q_kernel<<<ND/2/256, 256, 0, stream>>>(query, fc, fs, qr);
    transpose_v_kernel<<<dim3(SS/64, HD/64, BB*HH), 256, 0, stream>>>(value, vt);

    dim3 gg(DD/128, MTOT/128);     // 16 x 64
    gemm_kernel<0><<<gg, 256, 0, stream>>>(xb, kwb, key_b, fc, fs, (void*)kr);
    attn_kernel<<<dim3(8, BB*HH), 512, 0, stream>>>(qr, kr, vt, ao);
    gemm_kernel<1><<<gg, 256, 0, stream>>>(ao, pwb, proj_b, nullptr, nullptr, d_out);
}

// Round 4
// 565.034 us; speedup vs baseline: 1.0477x; 1.0477x over previous
//
#include <hip/hip_runtime.h>
#include <hip/hip_bf16.h>
#include <stdint.h>

#define BB 4
#define SS 2048
#define DD 2048
#define HH 16
#define HD 128
#define MTOT (BB*SS)   // 8192 rows for both big GEMMs

typedef __attribute__((ext_vector_type(8))) short short8;   // 8 bf16 (4 VGPRs)
typedef __attribute__((ext_vector_type(4))) float f32x4;    // MFMA C/D

__device__ __forceinline__ unsigned short f2bf(float f) {
    union { float f; unsigned int u; } v; v.f = f;
    unsigned int u = v.u;
    return (unsigned short)((u + 0x7FFFu + ((u >> 16) & 1u)) >> 16);  // RNE
}
// cheap round-half-up for nonnegative P values (2 VALU instead of 4)
__device__ __forceinline__ unsigned short f2bf_ru(float f) {
    union { float f; unsigned int u; } v; v.f = f;
    return (unsigned short)((v.u + 0x8000u) >> 16);
}

// ---------------------------------------------------------------- converts
__global__ __launch_bounds__(256) void convert_kernel(
    const float* __restrict__ src, unsigned short* __restrict__ dst, int n4) {
    int i = blockIdx.x * 256 + threadIdx.x;
    if (i >= n4) return;
    float4 v = ((const float4*)src)[i];
    unsigned int lo = (unsigned int)f2bf(v.x) | ((unsigned int)f2bf(v.y) << 16);
    unsigned int hi = (unsigned int)f2bf(v.z) | ((unsigned int)f2bf(v.w) << 16);
    ((uint2*)dst)[i] = make_uint2(lo, hi);
}

// RoPE on query + bf16 convert + PRE-SCALE by 1/sqrt(128)*log2(e) so the
// attention kernel's softmax uses exp2 with no per-score multiply.
__global__ __launch_bounds__(256) void rope_q_kernel(
    const float* __restrict__ q, const float* __restrict__ fc,
    const float* __restrict__ fs, unsigned short* __restrict__ dst) {
    const float scl2 = 0.08838834764831845f * 1.44269504088896f;
    int idx = blockIdx.x * 256 + threadIdx.x;          // pair index, 0..B*S*D/2
    int row   = idx >> 10;                             // b*S + s
    int s     = row & (SS - 1);
    int p     = idx & 63;                              // pos within head /2
    float2 t = ((const float2*)q)[idx];
    float c = fc[s*64 + p], sn = fs[s*64 + p];
    float o1 = (t.x*c - t.y*sn) * scl2;
    float o2 = (t.x*sn + t.y*c) * scl2;
    ((unsigned int*)dst)[idx] = (unsigned int)f2bf(o1) | ((unsigned int)f2bf(o2) << 16);
}

// value (B,S,H,HD) fp32 -> Vt (B,H,HD,S') bf16, where within each 64-s block
// the s-axis is PERMUTED: position k' = 4m+c holds original s = c*16+m.
// This makes attention's P-store a contiguous b64 write (P and V share the
// same k-permutation, so the PV dot product is unchanged). [R3-verified]
__global__ __launch_bounds__(256) void transpose_v_kernel(
    const float* __restrict__ v, unsigned short* __restrict__ vt) {
    __shared__ unsigned short tile[64][72];
    int bh = blockIdx.z;                   // b*16 + h
    int s0 = blockIdx.x * 64, d0 = blockIdx.y * 64;
    int t = threadIdx.x;
    #pragma unroll
    for (int it = 0; it < 4; ++it) {
        int i  = it*16 + (t >> 4);         // local s
        int j4 = t & 15;                   // float4 index along d
        float4 f = *(const float4*)(v +
            (((size_t)((bh >> 4)*SS + s0 + i)*HH + (bh & 15))*HD + d0 + j4*4));
        unsigned int lo = (unsigned int)f2bf(f.x) | ((unsigned int)f2bf(f.y) << 16);
        unsigned int hi = (unsigned int)f2bf(f.z) | ((unsigned int)f2bf(f.w) << 16);
        *(uint2*)&tile[i][j4*4] = make_uint2(lo, hi);
    }
    __syncthreads();
    unsigned int* vt32 = (unsigned int*)vt;
    #pragma unroll
    for (int it = 0; it < 8; ++it) {
        int task = it*256 + t;
        int tt = task & 31;                // output dword index within 64-block
        int d  = task >> 5;                // local d, 0..63
        // dword tt covers k' = 2tt, 2tt+1 -> original s = 32(tt&1)+(tt>>1) (+16)
        int slo = ((tt & 1) << 5) + (tt >> 1);
        unsigned int lo = tile[slo][d], hi = tile[slo + 16][d];
        vt32[((size_t)bh*HD + d0 + d)*(SS/2) + (s0 >> 1) + tt] = lo | (hi << 16);
    }
}

// ---------------------------------------------------------------- GEMM
// C[m,n] = sum_k A[m,k]*W[n,k] + bias[n].  A: MxK bf16 row-major, W: NxK bf16.
// MODE 0: fused RoPE epilogue, bf16 out (K projection).
// MODE 1: plain epilogue, fp32 out (output projection).
// XCD-chunked block swizzle (bijective, nwg=1024 % 8 == 0).
template<int MODE>
__global__ __launch_bounds__(256, 2) void gemm_kernel(
    const unsigned short* __restrict__ A, const unsigned short* __restrict__ W,
    const float* __restrict__ bias, const float* __restrict__ fc,
    const float* __restrict__ fs, void* __restrict__ out)
{
    __shared__ unsigned short As[128*32];
    __shared__ unsigned short Bs[128*32];
    const int K = DD;
    int L   = blockIdx.y * 16 + blockIdx.x;          // 0..1023, x-fastest
    int swz = (L & 7) * 128 + (L >> 3);              // XCD -> contiguous chunk
    int m0 = (swz >> 4) * 128, n0 = (swz & 15) * 128;
    int t = threadIdx.x, lane = t & 63, w = t >> 6;
    int wm = w >> 1, wn = w & 1;
    int l15 = lane & 15, quad = lane >> 4;

    f32x4 acc[4][4] = {};

    for (int k0 = 0; k0 < K; k0 += 32) {
        __syncthreads();                    // prior tile's LDS reads done
        #pragma unroll
        for (int i = 0; i < 2; ++i) {
            int ci  = i*256 + t;            // 16B chunk id, 0..511
            int row = ci >> 2;
            int ce  = (ci & 3) * 8;         // elem offset within 32-col row
            const unsigned short* ga = A + (size_t)(m0 + row) * K + k0 + ce;
            const unsigned short* gb = W + (size_t)(n0 + row) * K + k0 + ce;
            unsigned short* la = As + (size_t)(i*256 + w*64) * 8;  // wave-uniform
            unsigned short* lb = Bs + (size_t)(i*256 + w*64) * 8;
            __builtin_amdgcn_global_load_lds(
                (__attribute__((address_space(1))) void*)(uintptr_t)ga,
                (__attribute__((address_space(3))) void*)la, 16, 0, 0);
            __builtin_amdgcn_global_load_lds(
                (__attribute__((address_space(1))) void*)(uintptr_t)gb,
                (__attribute__((address_space(3))) void*)lb, 16, 0, 0);
        }
        __syncthreads();                    // drains vmcnt (global_load_lds)

        short8 af[4], bw[4];
        #pragma unroll
        for (int i = 0; i < 4; ++i) {
            af[i] = *(const short8*)(As + (size_t)(wm*64 + i*16 + l15)*32 + quad*8);
            bw[i] = *(const short8*)(Bs + (size_t)(wn*64 + i*16 + l15)*32 + quad*8);
        }
        #pragma unroll
        for (int i = 0; i < 4; ++i)
            #pragma unroll
            for (int j = 0; j < 4; ++j)
                acc[i][j] = __builtin_amdgcn_mfma_f32_16x16x32_bf16(
                    af[i], bw[j], acc[i][j], 0, 0, 0);
    }

    // epilogue: C/D layout col=lane&15, row=quad*4+reg  [m89-verified]
    #pragma unroll
    for (int i = 0; i < 4; ++i) {
        #pragma unroll
        for (int j = 0; j < 4; ++j) {
            int col = n0 + wn*64 + j*16 + l15;
            float bv = bias[col];
            #pragma unroll
            for (int r = 0; r < 4; ++r) {
                int row = m0 + wm*64 + i*16 + quad*4 + r;
                float v = acc[i][j][r] + bv;
                if (MODE == 0) {
                    // fused RoPE: pair partner is the adjacent lane
                    int s = row & (SS - 1);
                    int p = (col & 127) >> 1;
                    float other = __shfl_xor(v, 1);
                    float c = fc[s*64 + p], sn = fs[s*64 + p];
                    float res = (col & 1) ? (other*sn + v*c) : (v*c - other*sn);
                    ((unsigned short*)out)[(size_t)row*DD + col] = f2bf(res);
                } else {
                    ((float*)out)[(size_t)row*DD + col] = v;
                }
            }
        }
    }
}

// ---------------------------------------------------------------- attention
// Flash-style causal attention. Block = 8 waves / 512 threads; wave w owns
// 16 q-rows of a 128-row q-tile.
// Pipeline (per jt iteration):
//   barrier#1 = __syncthreads (drains K(jt), staged LAST iteration -> free)
//   issue V(jt) glds -> single V buffer; issue K(jt+1) glds -> K buf[pb^1]
//   QK^T(jt) from K buf[pb] + full softmax (hides V latency)
//   s_waitcnt vmcnt(2) + raw s_barrier  (V visible; K(jt+1) STAYS IN FLIGHT)
//   P-store + PV(jt)
// K double-buffered (32KB) + V single (16KB) + Ps (18KB) = 66KB -> 2 blk/CU
// (the 512-block grid caps at 2 blk/CU anyway — round-3's full dbuf at 84KB
// dropped to 1 blk/CU and regressed; this keeps occupancy AND the overlap).
// sched_barrier(0) pins: V glds issue before K glds (vmcnt order), and
// nothing crosses the counted waitcnt. Last iteration waits vmcnt(0).
// LDS rows UNPADDED (wave-uniform glds dest); bank conflicts avoided by an
// XOR chunk swizzle applied on the GLOBAL side (read with exact inverse).
// V's k-axis pre-permuted in Vt so P-stores are contiguous ds_write_b64.
// Defer-max (T13, THR=8 base-2). Deferred l-reduction: per-lane partials,
// one cross-lane reduce in the epilogue (-16 shuffles/iter).
// Q is pre-scaled by 1/sqrt(128)*log2e in rope_q.
// XCD swizzle: each XCD owns 8 consecutive bh.
__global__ __launch_bounds__(512, 4) void attn_kernel(
    const unsigned short* __restrict__ Q, const unsigned short* __restrict__ Kr,
    const unsigned short* __restrict__ Vt, unsigned short* __restrict__ O)
{
    constexpr int PSTR = 72;
    __shared__ unsigned short Ks[2*64*128];  // K tiles (dbuf), swizzled chunks
    __shared__ unsigned short VTs[128*64];   // V tile (single), swizzled chunks
    __shared__ unsigned short Ps[128*PSTR];  // rows [16w,16w+16) private to wave w

    int L   = blockIdx.y * 8 + blockIdx.x;   // 0..511, x-fastest
    int swz = (L & 7) * 64 + (L >> 3);       // XCD -> contiguous 64-block chunk
    int bh   = swz >> 3;                     // XCD x gets bh in [8x, 8x+8)
    int pair = swz & 7;                      // all 8 pairs of each bh

    int b = bh >> 4, h = bh & 15;
    size_t base  = (size_t)b*SS*DD + (size_t)h*HD;   // Q/K/O: + s*DD + d
    size_t vbase = (size_t)bh*HD*SS;                 // Vt: + d*SS + s'

    int t = threadIdx.x, lane = t & 63, w = t >> 6;
    int l15 = lane & 15, quad = lane >> 4;
    int l7 = l15 & 7;

    auto stageK = [&](int jt, int buf) {     // 2 glds/thread
        int j0s = jt * 64;
        #pragma unroll
        for (int i = 0; i < 2; ++i) {
            int ci  = i*512 + t;
            int row = ci >> 4;                 // 0..63
            int cc  = ci & 15;
            int gch = cc ^ (row & 7);          // global chunk (swizzle)
            const unsigned short* ga = Kr + base + (size_t)(j0s + row)*DD + gch*8;
            unsigned short* la = Ks + buf*(64*128) + (size_t)(i*512 + w*64)*8;
            __builtin_amdgcn_global_load_lds(
                (__attribute__((address_space(1))) void*)(uintptr_t)ga,
                (__attribute__((address_space(3))) void*)la, 16, 0, 0);
        }
    };
    auto stageV = [&](int jt) {              // 2 glds/thread
        int j0s = jt * 64;
        #pragma unroll
        for (int i = 0; i < 2; ++i) {
            int ci  = i*512 + t;
            int d   = ci >> 3;                 // 0..127
            int cc  = ci & 7;
            int gch = cc ^ (d & 7);
            const unsigned short* ga = Vt + vbase + (size_t)d*SS + j0s + gch*8;
            unsigned short* la = VTs + (size_t)(i*512 + w*64)*8;
            __builtin_amdgcn_global_load_lds(
                (__attribute__((address_space(1))) void*)(uintptr_t)ga,
                (__attribute__((address_space(3))) void*)la, 16, 0, 0);
        }
    };

    for (int ph = 0; ph < 2; ++ph) {
        int qt = ph ? (15 - pair) : pair;    // iters: (2p+2)+(2(15-p)+2)=34
        int q0 = qt * 128;
        int rw = q0 + w*16;                  // wave's first q-row

        // A-fragment of Q direct from global: m=l15 row, k=quad*8+j offset.
        short8 aq[4];
        #pragma unroll
        for (int kk = 0; kk < 4; ++kk)
            aq[kk] = *(const short8*)(Q + base +
                (size_t)(rw + l15)*DD + kk*32 + quad*8);

        float m_i[4], l_lane[4];
        #pragma unroll
        for (int r = 0; r < 4; ++r) { m_i[r] = -1e30f; l_lane[r] = 0.f; }
        f32x4 o_acc[8] = {};

        __syncthreads();                     // prev phase's LDS fully consumed
        stageK(0, 0);
        int jmax = 2*qt + 1;

        for (int jt = 0; jt <= jmax; ++jt) {
            int pb = jt & 1;
            int j0 = jt * 64;
            const unsigned short* Kb = Ks + pb*(64*128);

            __syncthreads();   // barrier#1: drains own K(jt) glds (hidden by
                               // prev iter's softmax+PV); WAR for VTs & Ks[pb^1]
            stageV(jt);
            __builtin_amdgcn_sched_barrier(0);      // V glds issue before K glds
            if (jt < jmax) stageK(jt + 1, pb ^ 1);  // in flight across barrier#2

            bool active = (j0 <= rw + 15);
            if (active) {
                // QK^T: wave's 16 q-rows x 64 k-cols (scores already *scl2*log2e)
                f32x4 sacc[4];
                #pragma unroll
                for (int c = 0; c < 4; ++c) {
                    sacc[c] = (f32x4){0.f, 0.f, 0.f, 0.f};
                    #pragma unroll
                    for (int kk = 0; kk < 4; ++kk) {
                        short8 bk = *(const short8*)(Kb +
                            (size_t)(c*16 + l15)*128 + ((kk*4 + quad) ^ l7)*8);
                        sacc[c] = __builtin_amdgcn_mfma_f32_16x16x32_bf16(aq[kk], bk, sacc[c], 0,0,0);
                    }
                }

                // causal mask (wave-uniform diag flag) + per-lane max
                bool diag = (j0 + 63 > rw);
                float pp[4][4], mt4[4];
                #pragma unroll
                for (int c = 0; c < 4; ++c)
                    #pragma unroll
                    for (int r = 0; r < 4; ++r) {
                        float v = sacc[c][r];
                        if (diag) {
                            int cg = j0 + c*16 + l15;         // global k col
                            int rg = rw + quad*4 + r;         // global q row
                            if (cg > rg) v = -1e30f;
                        }
                        pp[c][r] = v;
                    }
                #pragma unroll
                for (int r = 0; r < 4; ++r)
                    mt4[r] = fmaxf(fmaxf(pp[0][r], pp[1][r]), fmaxf(pp[2][r], pp[3][r]));

                // row-max across the 16 quad lanes + defer-max check
                bool grow = false;
                #pragma unroll
                for (int r = 0; r < 4; ++r) {
                    float m = mt4[r];
                    m = fmaxf(m, __shfl_xor(m, 1));
                    m = fmaxf(m, __shfl_xor(m, 2));
                    m = fmaxf(m, __shfl_xor(m, 4));
                    m = fmaxf(m, __shfl_xor(m, 8));
                    mt4[r] = m;
                    grow = grow || (m > m_i[r] + 8.0f);
                }
                if (__any(grow)) {             // rare after the first tiles
                    #pragma unroll
                    for (int r = 0; r < 4; ++r) {
                        float mn = fmaxf(m_i[r], mt4[r]);
                        float a  = exp2f(m_i[r] - mn);   // alpha (row-uniform)
                        m_i[r] = mn;
                        l_lane[r] *= a;
                        mt4[r] = a;
                    }
                    #pragma unroll
                    for (int f = 0; f < 8; ++f)
                        #pragma unroll
                        for (int r = 0; r < 4; ++r)
                            o_acc[f][r] *= mt4[r];
                }

                // P = exp2(s - m); packed b64 store, k' = 4*l15 + c (V-matched
                // perm); per-lane l partials (cross-lane reduce deferred).
                // Wave-private rows, same-wave DS ordering — no barrier needed.
                #pragma unroll
                for (int r = 0; r < 4; ++r) {
                    float e0 = exp2f(pp[0][r] - m_i[r]);
                    float e1 = exp2f(pp[1][r] - m_i[r]);
                    float e2 = exp2f(pp[2][r] - m_i[r]);
                    float e3 = exp2f(pp[3][r] - m_i[r]);
                    l_lane[r] += (e0 + e1) + (e2 + e3);
                    unsigned int lo = (unsigned int)f2bf_ru(e0) | ((unsigned int)f2bf_ru(e1) << 16);
                    unsigned int hi = (unsigned int)f2bf_ru(e2) | ((unsigned int)f2bf_ru(e3) << 16);
                    *(uint2*)&Ps[(size_t)(w*16 + quad*4 + r)*PSTR + l15*4] = make_uint2(lo, hi);
                }
            }

            // barrier#2: V visible to all waves; K(jt+1) stays in flight.
            __builtin_amdgcn_sched_barrier(0);
            if (jt < jmax) { asm volatile("s_waitcnt vmcnt(2)" ::: "memory"); }
            else           { asm volatile("s_waitcnt vmcnt(0)" ::: "memory"); }
            __builtin_amdgcn_s_barrier();
            __builtin_amdgcn_sched_barrier(0);

            if (active) {
                // PV: o += P(16x64) @ V(64x128) in permuted-k space
                #pragma unroll
                for (int kk2 = 0; kk2 < 2; ++kk2) {
                    short8 ap = *(const short8*)(Ps + (size_t)(w*16 + l15)*PSTR + kk2*32 + quad*8);
                    #pragma unroll
                    for (int f = 0; f < 8; ++f) {
                        short8 bv = *(const short8*)(VTs +
                            (size_t)(f*16 + l15)*64 + ((kk2*4 + quad) ^ l7)*8);
                        o_acc[f] = __builtin_amdgcn_mfma_f32_16x16x32_bf16(ap, bv, o_acc[f], 0,0,0);
                    }
                }
            }
        }

        // epilogue: reduce l partials across the 16 quad lanes, normalize, store
        #pragma unroll
        for (int r = 0; r < 4; ++r) {
            float s = l_lane[r];
            s += __shfl_xor(s, 1);
            s += __shfl_xor(s, 2);
            s += __shfl_xor(s, 4);
            s += __shfl_xor(s, 8);
            float inv = 1.0f / s;
            int srow = rw + quad*4 + r;
            #pragma unroll
            for (int f = 0; f < 8; ++f) {
                int d = f*16 + l15;
                O[base + (size_t)srow*DD + d] = f2bf(o_acc[f][r] * inv);
            }
        }
    }
}

// ---------------------------------------------------------------- launch
extern "C" void kernel_launch(void* const* d_in, const int* in_sizes, int n_in,
                              void* d_out, int out_size, void* d_ws, size_t ws_size,
                              hipStream_t stream) {
    const float* x      = (const float*)d_in[0];
    const float* query  = (const float*)d_in[1];
    const float* value  = (const float*)d_in[2];
    const float* fc     = (const float*)d_in[3];
    const float* fs     = (const float*)d_in[4];
    const float* key_w  = (const float*)d_in[5];
    const float* key_b  = (const float*)d_in[6];
    const float* proj_w = (const float*)d_in[7];
    const float* proj_b = (const float*)d_in[8];

    const int ND  = BB*SS*DD;      // 16777216
    const int NW  = DD*DD;         // 4194304
    unsigned short* xb  = (unsigned short*)d_ws;   // x bf16
    unsigned short* kwb = xb  + ND;                // key_w bf16
    unsigned short* pwb = kwb + NW;                // proj_w bf16
    unsigned short* qr  = pwb + NW;                // query roped+scaled bf16
    unsigned short* vt  = qr  + ND;                // value transposed+permuted bf16
    unsigned short* kr  = vt  + ND;                // k projected+roped bf16
    unsigned short* ao  = xb;                      // attn out reuses x region

    convert_kernel<<<ND/4/256, 256, 0, stream>>>(x, xb, ND/4);
    convert_kernel<<<NW/4/256, 256, 0, stream>>>(key_w, kwb, NW/4);
    convert_kernel<<<NW/4/256, 256, 0, stream>>>(proj_w, pwb, NW/4);
    rope_q_kernel<<<ND/2/256, 256, 0, stream>>>(query, fc, fs, qr);
    transpose_v_kernel<<<dim3(SS/64, HD/64, BB*HH), 256, 0, stream>>>(value, vt);

    dim3 gg(DD/128, MTOT/128);     // 16 x 64
    gemm_kernel<0><<<gg, 256, 0, stream>>>(xb, kwb, key_b, fc, fs, (void*)kr);
    attn_kernel<<<dim3(8, BB*HH), 512, 0, stream>>>(qr, kr, vt, ao);
    gemm_kernel<1><<<gg, 256, 0, stream>>>(ao, pwb, proj_b, nullptr, nullptr, d_out);
}

// Round 6
// 544.446 us; speedup vs baseline: 1.0874x; 1.0378x over previous
//
#include <hip/hip_runtime.h>
#include <hip/hip_bf16.h>
#include <stdint.h>

#define BB 4
#define SS 2048
#define DD 2048
#define HH 16
#define HD 128
#define MTOT (BB*SS)   // 8192 rows for both big GEMMs

typedef __attribute__((ext_vector_type(8))) short short8;   // 8 bf16 (4 VGPRs)
typedef __attribute__((ext_vector_type(4))) float f32x4;    // MFMA C/D

__device__ __forceinline__ unsigned short f2bf(float f) {
    union { float f; unsigned int u; } v; v.f = f;
    unsigned int u = v.u;
    return (unsigned short)((u + 0x7FFFu + ((u >> 16) & 1u)) >> 16);  // RNE
}
// cheap round-half-up for nonnegative P values (2 VALU instead of 4)
__device__ __forceinline__ unsigned short f2bf_ru(float f) {
    union { float f; unsigned int u; } v; v.f = f;
    return (unsigned short)((v.u + 0x8000u) >> 16);
}

// ---------------------------------------------------------------- converts
__global__ __launch_bounds__(256) void convert_kernel(
    const float* __restrict__ src, unsigned short* __restrict__ dst, int n4) {
    int i = blockIdx.x * 256 + threadIdx.x;
    if (i >= n4) return;
    float4 v = ((const float4*)src)[i];
    unsigned int lo = (unsigned int)f2bf(v.x) | ((unsigned int)f2bf(v.y) << 16);
    unsigned int hi = (unsigned int)f2bf(v.z) | ((unsigned int)f2bf(v.w) << 16);
    ((uint2*)dst)[i] = make_uint2(lo, hi);
}

// RoPE on query + bf16 convert + PRE-SCALE by 1/sqrt(128)*log2(e) so the
// attention kernel's softmax uses exp2 with no per-score multiply.
__global__ __launch_bounds__(256) void rope_q_kernel(
    const float* __restrict__ q, const float* __restrict__ fc,
    const float* __restrict__ fs, unsigned short* __restrict__ dst) {
    const float scl2 = 0.08838834764831845f * 1.44269504088896f;
    int idx = blockIdx.x * 256 + threadIdx.x;          // pair index, 0..B*S*D/2
    int row   = idx >> 10;                             // b*S + s
    int s     = row & (SS - 1);
    int p     = idx & 63;                              // pos within head /2
    float2 t = ((const float2*)q)[idx];
    float c = fc[s*64 + p], sn = fs[s*64 + p];
    float o1 = (t.x*c - t.y*sn) * scl2;
    float o2 = (t.x*sn + t.y*c) * scl2;
    ((unsigned int*)dst)[idx] = (unsigned int)f2bf(o1) | ((unsigned int)f2bf(o2) << 16);
}

// value (B,S,H,HD) fp32 -> Vt (B,H,HD,S') bf16, where within each 64-s block
// the s-axis is PERMUTED: position k' = 4m+c holds original s = c*16+m.
// This makes attention's P-store a contiguous b64 write (P and V share the
// same k-permutation, so the PV dot product is unchanged). [R3-verified]
__global__ __launch_bounds__(256) void transpose_v_kernel(
    const float* __restrict__ v, unsigned short* __restrict__ vt) {
    __shared__ unsigned short tile[64][72];
    int bh = blockIdx.z;                   // b*16 + h
    int s0 = blockIdx.x * 64, d0 = blockIdx.y * 64;
    int t = threadIdx.x;
    #pragma unroll
    for (int it = 0; it < 4; ++it) {
        int i  = it*16 + (t >> 4);         // local s
        int j4 = t & 15;                   // float4 index along d
        float4 f = *(const float4*)(v +
            (((size_t)((bh >> 4)*SS + s0 + i)*HH + (bh & 15))*HD + d0 + j4*4));
        unsigned int lo = (unsigned int)f2bf(f.x) | ((unsigned int)f2bf(f.y) << 16);
        unsigned int hi = (unsigned int)f2bf(f.z) | ((unsigned int)f2bf(f.w) << 16);
        *(uint2*)&tile[i][j4*4] = make_uint2(lo, hi);
    }
    __syncthreads();
    unsigned int* vt32 = (unsigned int*)vt;
    #pragma unroll
    for (int it = 0; it < 8; ++it) {
        int task = it*256 + t;
        int tt = task & 31;                // output dword index within 64-block
        int d  = task >> 5;                // local d, 0..63
        // dword tt covers k' = 2tt, 2tt+1 -> original s = 32(tt&1)+(tt>>1) (+16)
        int slo = ((tt & 1) << 5) + (tt >> 1);
        unsigned int lo = tile[slo][d], hi = tile[slo + 16][d];
        vt32[((size_t)bh*HD + d0 + d)*(SS/2) + (s0 >> 1) + tt] = lo | (hi << 16);
    }
}

// ---------------------------------------------------------------- GEMM
// C[m,n] = sum_k A[m,k]*W[n,k] + bias[n].  A: MxK bf16 row-major, W: NxK bf16.
// MODE 0: fused RoPE epilogue, bf16 out (K projection).
// MODE 1: plain epilogue, fp32 out (output projection).
// BK=64: 32 MFMA per barrier-pair (2x the m97 BK=32 amortization of the
// vmcnt(0) drain). 64-col rows stride 128B in LDS -> 16-way read conflict
// if linear, so the attn-verified XOR chunk swizzle is applied:
//   LDS[row][cc] = GLOBAL[row][cc ^ (row&7)]  (16B chunks, 8/row)
// linear LDS dest (glds constraint) + pre-swizzled global src + inverse on
// the ds_read side (rule #21: both-sides-or-neither).
// XCD-chunked block swizzle (bijective, nwg=1024 % 8 == 0).
template<int MODE>
__global__ __launch_bounds__(256, 3) void gemm_kernel(
    const unsigned short* __restrict__ A, const unsigned short* __restrict__ W,
    const float* __restrict__ bias, const float* __restrict__ fc,
    const float* __restrict__ fs, void* __restrict__ out)
{
    __shared__ unsigned short As[128*64];
    __shared__ unsigned short Bs[128*64];
    const int K = DD;
    int L   = blockIdx.y * 16 + blockIdx.x;          // 0..1023, x-fastest
    int swz = (L & 7) * 128 + (L >> 3);              // XCD -> contiguous chunk
    int m0 = (swz >> 4) * 128, n0 = (swz & 15) * 128;
    int t = threadIdx.x, lane = t & 63, w = t >> 6;
    int wm = w >> 1, wn = w & 1;
    int l15 = lane & 15, quad = lane >> 4;
    int l7 = l15 & 7;

    f32x4 acc[4][4] = {};

    for (int k0 = 0; k0 < K; k0 += 64) {
        __syncthreads();                    // prior tile's LDS reads done
        #pragma unroll
        for (int i = 0; i < 4; ++i) {
            int ci  = i*256 + t;            // 16B chunk id, 0..1023
            int row = ci >> 3;              // 0..127
            int cc  = ci & 7;               // LDS chunk within 64-col row
            int gch = cc ^ (row & 7);       // global chunk (swizzle)
            const unsigned short* ga = A + (size_t)(m0 + row) * K + k0 + gch*8;
            const unsigned short* gb = W + (size_t)(n0 + row) * K + k0 + gch*8;
            unsigned short* la = As + (size_t)(i*256 + w*64) * 8;  // wave-uniform
            unsigned short* lb = Bs + (size_t)(i*256 + w*64) * 8;
            __builtin_amdgcn_global_load_lds(
                (__attribute__((address_space(1))) void*)(uintptr_t)ga,
                (__attribute__((address_space(3))) void*)la, 16, 0, 0);
            __builtin_amdgcn_global_load_lds(
                (__attribute__((address_space(1))) void*)(uintptr_t)gb,
                (__attribute__((address_space(3))) void*)lb, 16, 0, 0);
        }
        __syncthreads();                    // drains vmcnt (global_load_lds)

        #pragma unroll
        for (int kk = 0; kk < 2; ++kk) {
            short8 af[4], bw[4];
            #pragma unroll
            for (int i = 0; i < 4; ++i) {
                int ch = (kk*4 + quad) ^ l7;    // inverse swizzle
                af[i] = *(const short8*)(As + (size_t)(wm*64 + i*16 + l15)*64 + ch*8);
                bw[i] = *(const short8*)(Bs + (size_t)(wn*64 + i*16 + l15)*64 + ch*8);
            }
            #pragma unroll
            for (int i = 0; i < 4; ++i)
                #pragma unroll
                for (int j = 0; j < 4; ++j)
                    acc[i][j] = __builtin_amdgcn_mfma_f32_16x16x32_bf16(
                        af[i], bw[j], acc[i][j], 0, 0, 0);
        }
    }

    // epilogue: C/D layout col=lane&15, row=quad*4+reg  [m89-verified]
    #pragma unroll
    for (int i = 0; i < 4; ++i) {
        #pragma unroll
        for (int j = 0; j < 4; ++j) {
            int col = n0 + wn*64 + j*16 + l15;
            float bv = bias[col];
            #pragma unroll
            for (int r = 0; r < 4; ++r) {
                int row = m0 + wm*64 + i*16 + quad*4 + r;
                float v = acc[i][j][r] + bv;
                if (MODE == 0) {
                    // fused RoPE: pair partner is the adjacent lane
                    int s = row & (SS - 1);
                    int p = (col & 127) >> 1;
                    float other = __shfl_xor(v, 1);
                    float c = fc[s*64 + p], sn = fs[s*64 + p];
                    float res = (col & 1) ? (other*sn + v*c) : (v*c - other*sn);
                    ((unsigned short*)out)[(size_t)row*DD + col] = f2bf(res);
                } else {
                    ((float*)out)[(size_t)row*DD + col] = v;
                }
            }
        }
    }
}

// ---------------------------------------------------------------- attention
// Flash-style causal attention. Block = 8 waves / 512 threads; wave w owns
// 16 q-rows of a 128-row q-tile.
// Pipeline (per jt iteration):
//   barrier#1 = __syncthreads (drains K(jt), staged LAST iteration -> free)
//   issue V(jt) glds -> single V buffer; issue K(jt+1) glds -> K buf[pb^1]
//   QK^T(jt) from K buf[pb] + full softmax (hides V latency)
//   s_waitcnt vmcnt(2) + raw s_barrier  (V visible; K(jt+1) STAYS IN FLIGHT)
//   P-store + PV(jt)
// K double-buffered (32KB) + V single (16KB) + Ps (18KB) = 66KB -> 2 blk/CU.
// LAZY max-reduce: the 16-shuffle cross-lane row-max runs ONLY when some
// lane's local max exceeds m_i + 8 (any-lane-exceeds <=> true-max-exceeds,
// so this is exactly defer-max semantics); common path saves 16 ds_swizzle
// + 16 fmax per iteration. [R5]
// LDS rows UNPADDED (wave-uniform glds dest); bank conflicts avoided by an
// XOR chunk swizzle applied on the GLOBAL side (read with exact inverse).
// V's k-axis pre-permuted in Vt so P-stores are contiguous ds_write_b64.
// Deferred l-reduction: per-lane partials, one cross-lane reduce in epilogue.
// Q is pre-scaled by 1/sqrt(128)*log2e in rope_q.
// XCD swizzle: each XCD owns 8 consecutive bh.
__global__ __launch_bounds__(512, 4) void attn_kernel(
    const unsigned short* __restrict__ Q, const unsigned short* __restrict__ Kr,
    const unsigned short* __restrict__ Vt, unsigned short* __restrict__ O)
{
    constexpr int PSTR = 72;
    __shared__ unsigned short Ks[2*64*128];  // K tiles (dbuf), swizzled chunks
    __shared__ unsigned short VTs[128*64];   // V tile (single), swizzled chunks
    __shared__ unsigned short Ps[128*PSTR];  // rows [16w,16w+16) private to wave w

    int L   = blockIdx.y * 8 + blockIdx.x;   // 0..511, x-fastest
    int swz = (L & 7) * 64 + (L >> 3);       // XCD -> contiguous 64-block chunk
    int bh   = swz >> 3;                     // XCD x gets bh in [8x, 8x+8)
    int pair = swz & 7;                      // all 8 pairs of each bh

    int b = bh >> 4, h = bh & 15;
    size_t base  = (size_t)b*SS*DD + (size_t)h*HD;   // Q/K/O: + s*DD + d
    size_t vbase = (size_t)bh*HD*SS;                 // Vt: + d*SS + s'

    int t = threadIdx.x, lane = t & 63, w = t >> 6;
    int l15 = lane & 15, quad = lane >> 4;
    int l7 = l15 & 7;

    auto stageK = [&](int jt, int buf) {     // 2 glds/thread
        int j0s = jt * 64;
        #pragma unroll
        for (int i = 0; i < 2; ++i) {
            int ci  = i*512 + t;
            int row = ci >> 4;                 // 0..63
            int cc  = ci & 15;
            int gch = cc ^ (row & 7);          // global chunk (swizzle)
            const unsigned short* ga = Kr + base + (size_t)(j0s + row)*DD + gch*8;
            unsigned short* la = Ks + buf*(64*128) + (size_t)(i*512 + w*64)*8;
            __builtin_amdgcn_global_load_lds(
                (__attribute__((address_space(1))) void*)(uintptr_t)ga,
                (__attribute__((address_space(3))) void*)la, 16, 0, 0);
        }
    };
    auto stageV = [&](int jt) {              // 2 glds/thread
        int j0s = jt * 64;
        #pragma unroll
        for (int i = 0; i < 2; ++i) {
            int ci  = i*512 + t;
            int d   = ci >> 3;                 // 0..127
            int cc  = ci & 7;
            int gch = cc ^ (d & 7);
            const unsigned short* ga = Vt + vbase + (size_t)d*SS + j0s + gch*8;
            unsigned short* la = VTs + (size_t)(i*512 + w*64)*8;
            __builtin_amdgcn_global_load_lds(
                (__attribute__((address_space(1))) void*)(uintptr_t)ga,
                (__attribute__((address_space(3))) void*)la, 16, 0, 0);
        }
    };

    for (int ph = 0; ph < 2; ++ph) {
        int qt = ph ? (15 - pair) : pair;    // iters: (2p+2)+(2(15-p)+2)=34
        int q0 = qt * 128;
        int rw = q0 + w*16;                  // wave's first q-row

        // A-fragment of Q direct from global: m=l15 row, k=quad*8+j offset.
        short8 aq[4];
        #pragma unroll
        for (int kk = 0; kk < 4; ++kk)
            aq[kk] = *(const short8*)(Q + base +
                (size_t)(rw + l15)*DD + kk*32 + quad*8);

        float m_i[4], l_lane[4];
        #pragma unroll
        for (int r = 0; r < 4; ++r) { m_i[r] = -1e30f; l_lane[r] = 0.f; }
        f32x4 o_acc[8] = {};

        __syncthreads();                     // prev phase's LDS fully consumed
        stageK(0, 0);
        int jmax = 2*qt + 1;

        for (int jt = 0; jt <= jmax; ++jt) {
            int pb = jt & 1;
            int j0 = jt * 64;
            const unsigned short* Kb = Ks + pb*(64*128);

            __syncthreads();   // barrier#1: drains own K(jt) glds (hidden by
                               // prev iter's softmax+PV); WAR for VTs & Ks[pb^1]
            stageV(jt);
            __builtin_amdgcn_sched_barrier(0);      // V glds issue before K glds
            if (jt < jmax) stageK(jt + 1, pb ^ 1);  // in flight across barrier#2

            bool active = (j0 <= rw + 15);
            if (active) {
                // QK^T: wave's 16 q-rows x 64 k-cols (scores already *scl2*log2e)
                f32x4 sacc[4];
                #pragma unroll
                for (int c = 0; c < 4; ++c) {
                    sacc[c] = (f32x4){0.f, 0.f, 0.f, 0.f};
                    #pragma unroll
                    for (int kk = 0; kk < 4; ++kk) {
                        short8 bk = *(const short8*)(Kb +
                            (size_t)(c*16 + l15)*128 + ((kk*4 + quad) ^ l7)*8);
                        sacc[c] = __builtin_amdgcn_mfma_f32_16x16x32_bf16(aq[kk], bk, sacc[c], 0,0,0);
                    }
                }

                // causal mask (wave-uniform diag flag) + per-lane max
                bool diag = (j0 + 63 > rw);
                float pp[4][4], mt4[4];
                #pragma unroll
                for (int c = 0; c < 4; ++c)
                    #pragma unroll
                    for (int r = 0; r < 4; ++r) {
                        float v = sacc[c][r];
                        if (diag) {
                            int cg = j0 + c*16 + l15;         // global k col
                            int rg = rw + quad*4 + r;         // global q row
                            if (cg > rg) v = -1e30f;
                        }
                        pp[c][r] = v;
                    }
                #pragma unroll
                for (int r = 0; r < 4; ++r)
                    mt4[r] = fmaxf(fmaxf(pp[0][r], pp[1][r]), fmaxf(pp[2][r], pp[3][r]));

                // LAZY defer-max: full cross-lane reduce only when needed.
                bool growl = false;
                #pragma unroll
                for (int r = 0; r < 4; ++r)
                    growl = growl || (mt4[r] > m_i[r] + 8.0f);
                if (__any(growl)) {            // rare after the first tiles
                    #pragma unroll
                    for (int r = 0; r < 4; ++r) {
                        float m = mt4[r];
                        m = fmaxf(m, __shfl_xor(m, 1));
                        m = fmaxf(m, __shfl_xor(m, 2));
                        m = fmaxf(m, __shfl_xor(m, 4));
                        m = fmaxf(m, __shfl_xor(m, 8));
                        float mn = fmaxf(m_i[r], m);
                        float a  = exp2f(m_i[r] - mn);   // alpha (row-uniform)
                        m_i[r] = mn;
                        l_lane[r] *= a;
                        mt4[r] = a;
                    }
                    #pragma unroll
                    for (int f = 0; f < 8; ++f)
                        #pragma unroll
                        for (int r = 0; r < 4; ++r)
                            o_acc[f][r] *= mt4[r];
                }

                // P = exp2(s - m); packed b64 store, k' = 4*l15 + c (V-matched
                // perm); per-lane l partials (cross-lane reduce deferred).
                // Wave-private rows, same-wave DS ordering — no barrier needed.
                #pragma unroll
                for (int r = 0; r < 4; ++r) {
                    float e0 = exp2f(pp[0][r] - m_i[r]);
                    float e1 = exp2f(pp[1][r] - m_i[r]);
                    float e2 = exp2f(pp[2][r] - m_i[r]);
                    float e3 = exp2f(pp[3][r] - m_i[r]);
                    l_lane[r] += (e0 + e1) + (e2 + e3);
                    unsigned int lo = (unsigned int)f2bf_ru(e0) | ((unsigned int)f2bf_ru(e1) << 16);
                    unsigned int hi = (unsigned int)f2bf_ru(e2) | ((unsigned int)f2bf_ru(e3) << 16);
                    *(uint2*)&Ps[(size_t)(w*16 + quad*4 + r)*PSTR + l15*4] = make_uint2(lo, hi);
                }
            }

            // barrier#2: V visible to all waves; K(jt+1) stays in flight.
            __builtin_amdgcn_sched_barrier(0);
            if (jt < jmax) { asm volatile("s_waitcnt vmcnt(2)" ::: "memory"); }
            else           { asm volatile("s_waitcnt vmcnt(0)" ::: "memory"); }
            __builtin_amdgcn_s_barrier();
            __builtin_amdgcn_sched_barrier(0);

            if (active) {
                // PV: o += P(16x64) @ V(64x128) in permuted-k space
                #pragma unroll
                for (int kk2 = 0; kk2 < 2; ++kk2) {
                    short8 ap = *(const short8*)(Ps + (size_t)(w*16 + l15)*PSTR + kk2*32 + quad*8);
                    #pragma unroll
                    for (int f = 0; f < 8; ++f) {
                        short8 bv = *(const short8*)(VTs +
                            (size_t)(f*16 + l15)*64 + ((kk2*4 + quad) ^ l7)*8);
                        o_acc[f] = __builtin_amdgcn_mfma_f32_16x16x32_bf16(ap, bv, o_acc[f], 0,0,0);
                    }
                }
            }
        }

        // epilogue: reduce l partials across the 16 quad lanes, normalize, store
        #pragma unroll
        for (int r = 0; r < 4; ++r) {
            float s = l_lane[r];
            s += __shfl_xor(s, 1);
            s += __shfl_xor(s, 2);
            s += __shfl_xor(s, 4);
            s += __shfl_xor(s, 8);
            float inv = 1.0f / s;
            int srow = rw + quad*4 + r;
            #pragma unroll
            for (int f = 0; f < 8; ++f) {
                int d = f*16 + l15;
                O[base + (size_t)srow*DD + d] = f2bf(o_acc[f][r] * inv);
            }
        }
    }
}

// ---------------------------------------------------------------- launch
extern "C" void kernel_launch(void* const* d_in, const int* in_sizes, int n_in,
                              void* d_out, int out_size, void* d_ws, size_t ws_size,
                              hipStream_t stream) {
    const float* x      = (const float*)d_in[0];
    const float* query  = (const float*)d_in[1];
    const float* value  = (const float*)d_in[2];
    const float* fc     = (const float*)d_in[3];
    const float* fs     = (const float*)d_in[4];
    const float* key_w  = (const float*)d_in[5];
    const float* key_b  = (const float*)d_in[6];
    const float* proj_w = (const float*)d_in[7];
    const float* proj_b = (const float*)d_in[8];

    const int ND  = BB*SS*DD;      // 16777216
    const int NW  = DD*DD;         // 4194304
    unsigned short* xb  = (unsigned short*)d_ws;   // x bf16
    unsigned short* kwb = xb  + ND;                // key_w bf16
    unsigned short* pwb = kwb + NW;                // proj_w bf16
    unsigned short* qr  = pwb + NW;                // query roped+scaled bf16
    unsigned short* vt  = qr  + ND;                // value transposed+permuted bf16
    unsigned short* kr  = vt  + ND;                // k projected+roped bf16
    unsigned short* ao  = xb;                      // attn out reuses x region

    convert_kernel<<<ND/4/256, 256, 0, stream>>>(x, xb, ND/4);
    convert_kernel<<<NW/4/256, 256, 0, stream>>>(key_w, kwb, NW/4);
    convert_kernel<<<NW/4/256, 256, 0, stream>>>(proj_w, pwb, NW/4);
    rope_q_kernel<<<ND/2/256, 256, 0, stream>>>(query, fc, fs, qr);
    transpose_v_kernel<<<dim3(SS/64, HD/64, BB*HH), 256, 0, stream>>>(value, vt);

    dim3 gg(DD/128, MTOT/128);     // 16 x 64
    gemm_kernel<0><<<gg, 256, 0, stream>>>(xb, kwb, key_b, fc, fs, (void*)kr);
    attn_kernel<<<dim3(8, BB*HH), 512, 0, stream>>>(qr, kr, vt, ao);
    gemm_kernel<1><<<gg, 256, 0, stream>>>(ao, pwb, proj_b, nullptr, nullptr, d_out);
}